// Round 8
// baseline (155.881 us; speedup 1.0000x reference)
//
#include <hip/hip_runtime.h>
#include <stdint.h>

// ---------------------------------------------------------------------------
// GPT-2 attention block on gfx950.  B=4, S=2048, D=1024, H=16, HD=64.
//   1. cvt_bf16:  X fp32 -> bf16
//   2. wt4:       {Wq,Wk,Wv,Wo} fp32 [K][N] -> bf16 [N][K]
//   3. gemm2<0>:  QKV = X@[Wq|Wk|Wv]+b; Q,K -> [B,H,S,64], V -> Vt [B,H,64,S]
//                 128x128 tile, 4 waves, BK=32, 3-buf LDS ring (48KB ->
//                 3 blocks/CU), counted vmcnt(4), XOR-swizzled LDS,
//                 XCD-chunked A panels (8 m-tiles/XCD).
//   4. attn:      flash causal attention, fixed-shift softmax, 3-buf ring,
//                 row-sums via MFMA ones-column.
//   5. gemm2<1>:  out = attn@Wo + bo, fp32
// ---------------------------------------------------------------------------

#define GAS __attribute__((address_space(1)))
#define LAS __attribute__((address_space(3)))

typedef __attribute__((ext_vector_type(4))) float f32x4;
typedef __attribute__((ext_vector_type(8))) short bf16x8;

__device__ __forceinline__ short f2bf(float f) {
  union { float f; uint32_t u; } v; v.f = f;
  uint32_t r = v.u + 0x7fffu + ((v.u >> 16) & 1u);  // RNE
  return (short)(r >> 16);
}

__device__ __forceinline__ float bf2f(short s) {
  union { uint32_t u; float f; } v;
  v.u = ((uint32_t)(uint16_t)s) << 16;
  return v.f;
}

__device__ __forceinline__ uint32_t cvt_pk_bf16(float lo, float hi) {
  uint32_t r;
  asm("v_cvt_pk_bf16_f32 %0, %1, %2" : "=v"(r) : "v"(lo), "v"(hi));
  return r;
}

__device__ __forceinline__ void gload_lds16(const void* g, void* l) {
  // 16B per lane; LDS dest = wave-uniform base + lane*16 (linear)
  __builtin_amdgcn_global_load_lds((const GAS void*)g, (LAS void*)l, 16, 0, 0);
}

// Group gate: counted vmcnt + raw barrier; sched_barrier pins motion both ways.
#define GATE(N)                                            \
  __builtin_amdgcn_sched_barrier(0);                       \
  asm volatile("s_waitcnt vmcnt(" #N ")" ::: "memory");    \
  __builtin_amdgcn_s_barrier();                            \
  __builtin_amdgcn_sched_barrier(0);

// ---------------- fp32 -> bf16 convert ----------------
__global__ __launch_bounds__(256) void cvt_bf16_kernel(const float* __restrict__ in,
                                                       short* __restrict__ out, int n4) {
  int i = blockIdx.x * blockDim.x + threadIdx.x;
  int stride = gridDim.x * blockDim.x;
  for (int idx = i; idx < n4; idx += stride) {
    float4 v = ((const float4*)in)[idx];
    short4 o;
    o.x = f2bf(v.x); o.y = f2bf(v.y); o.z = f2bf(v.z); o.w = f2bf(v.w);
    ((short4*)out)[idx] = o;
  }
}

// ---------------- 4x W [1024][1024] fp32 -> Wt bf16 [N][K] ----------------
__global__ __launch_bounds__(256) void wt4_kernel(const float* __restrict__ W0,
                                                  const float* __restrict__ W1,
                                                  const float* __restrict__ W2,
                                                  const float* __restrict__ W3,
                                                  short* __restrict__ Wt) {
  __shared__ short tile[64][65];
  const float* W = (blockIdx.z == 0) ? W0 : (blockIdx.z == 1) ? W1
                   : (blockIdx.z == 2) ? W2 : W3;
  short* dst = Wt + ((size_t)blockIdx.z << 20);
  const int k0 = blockIdx.x * 64, n0 = blockIdx.y * 64;
  const int t = threadIdx.x;
#pragma unroll
  for (int i = 0; i < 16; ++i) {
    int r = (t >> 6) + i * 4, c = t & 63;
    tile[r][c] = f2bf(W[(size_t)(k0 + r) * 1024 + n0 + c]);
  }
  __syncthreads();
#pragma unroll
  for (int i = 0; i < 16; ++i) {
    int r = (t >> 6) + i * 4, c = t & 63;
    dst[(size_t)(n0 + r) * 1024 + k0 + c] = tile[c][r];
  }
}

// ---------------- deep-pipelined bf16 GEMM, 128x128 ----------------
// C[M,N] = A[M,1024] @ Bt[N,1024]^T + bias.  BM=BN=128, BK=32.
// 256 thr = 4 waves (2M x 2N), wave tile 64x64 (4x4 16x16 frags).
// LDS: 3-buffer ring, 16KB each (A 8KB + B 8KB) = 48KB -> 3 blocks/CU.
// 4 loads/wave/tile; gate vmcnt(4) (tile j done, j+1 in flight);
// stage(j+2) right after the gate.  XCD x owns m-tiles [8x..8x+7].
template <int MODE>
__global__ __launch_bounds__(256, 3) void gemm2(const short* __restrict__ A,
                                                const short* __restrict__ Bt,
                                                const float* __restrict__ b0,
                                                const float* __restrict__ b1,
                                                const float* __restrict__ b2,
                                                void* __restrict__ O0,
                                                void* __restrict__ O1,
                                                void* __restrict__ O2) {
  __shared__ short lds[3][8192];  // [buf][ A:0..4095 | B:4096..8191 ]
  const int xcd = (int)blockIdx.x & 7;
  const int t = (int)blockIdx.x >> 3;
  const int m0 = (xcd * 8 + (t & 7)) * 128;  // 8 m-tiles chunked per XCD
  const int n0 = (t >> 3) * 128;             // N advances within chunk
  const int tid = threadIdx.x;
  const int lane = tid & 63, w = tid >> 6;
  const int l15 = lane & 15, lg = lane >> 4;
  const int wm = w >> 1, wn = w & 1;

  // per-lane swizzled global source pointers (2 A-loads + 2 B-loads per wave)
  const short* ag[2];
  const short* bg[2];
#pragma unroll
  for (int i = 0; i < 2; ++i) {
    const int P = w * 64 + i * 256 + lane;  // physical 16B block 0..511
    const int L = P ^ ((P >> 3) & 7);       // logical: row L>>2, chunk L&3
    ag[i] = A + (size_t)(m0 + (L >> 2)) * 1024 + (L & 3) * 8;
    bg[i] = Bt + (size_t)(n0 + (L >> 2)) * 1024 + (L & 3) * 8;
  }

  // swizzled LDS read offsets (shorts) for the 4+4 fragments
  int aof[4], bof[4];
#pragma unroll
  for (int mf = 0; mf < 4; ++mf) {
    const int L = (wm * 64 + mf * 16 + l15) * 4 + lg;
    aof[mf] = (L ^ ((L >> 3) & 7)) * 8;
  }
#pragma unroll
  for (int nf = 0; nf < 4; ++nf) {
    const int L = (wn * 64 + nf * 16 + l15) * 4 + lg;
    bof[nf] = (L ^ ((L >> 3) & 7)) * 8;
  }

  f32x4 acc[4][4];
#pragma unroll
  for (int i = 0; i < 4; ++i)
#pragma unroll
    for (int j = 0; j < 4; ++j) acc[i][j] = (f32x4){0.f, 0.f, 0.f, 0.f};

  auto stage = [&](int bi, int kt) {
    short* As = &lds[bi][0];
    short* Bs = &lds[bi][4096];
#pragma unroll
    for (int i = 0; i < 2; ++i) {
      gload_lds16(ag[i] + kt * 32, As + (w * 64 + i * 256) * 8);
      gload_lds16(bg[i] + kt * 32, Bs + (w * 64 + i * 256) * 8);
    }
  };

  auto compute = [&](int bi) {
    const short* As = &lds[bi][0];
    const short* Bs = &lds[bi][4096];
    bf16x8 a[4], b[4];
#pragma unroll
    for (int mf = 0; mf < 4; ++mf) a[mf] = *(const bf16x8*)&As[aof[mf]];
#pragma unroll
    for (int nf = 0; nf < 4; ++nf) b[nf] = *(const bf16x8*)&Bs[bof[nf]];
    __builtin_amdgcn_s_setprio(1);
#pragma unroll
    for (int mf = 0; mf < 4; ++mf)
#pragma unroll
      for (int nf = 0; nf < 4; ++nf)
        acc[mf][nf] =
            __builtin_amdgcn_mfma_f32_16x16x32_bf16(a[mf], b[nf], acc[mf][nf], 0, 0, 0);
    __builtin_amdgcn_s_setprio(0);
  };

  // prologue: 2 tiles in flight (8 loads/wave)
  stage(0, 0);
  stage(1, 1);

  // main loop: j=0..29 (stage j+2 = 2..31); buffer j%3
  int bi = 0;
  for (int j = 0; j < 30; ++j) {
    GATE(4)
    int nb = bi + 2; if (nb >= 3) nb -= 3;
    stage(nb, j + 2);
    compute(bi);
    bi = bi + 1 == 3 ? 0 : bi + 1;
  }
  // tail: drain 4 -> 0
  GATE(4) compute(bi);
  bi = bi + 1 == 3 ? 0 : bi + 1;
  GATE(0) compute(bi);

  // ---------------- epilogue; frag: row = lg*4+rr, col = l15 ----------------
  if (MODE == 1) {
    float* dst = (float*)O0;
#pragma unroll
    for (int mf = 0; mf < 4; ++mf)
#pragma unroll
      for (int nf = 0; nf < 4; ++nf) {
        const int col = n0 + wn * 64 + nf * 16 + l15;
        const float bv = b0[col];
#pragma unroll
        for (int rr = 0; rr < 4; ++rr) {
          const int row = m0 + wm * 64 + mf * 16 + lg * 4 + rr;
          dst[(size_t)row * 1024 + col] = acc[mf][nf][rr] + bv;
        }
      }
  } else {
    const int mat = n0 >> 10;  // 0=Q 1=K 2=V
    const int nc0 = n0 & 1023;
    const float* bias = (mat == 0) ? b0 : (mat == 1) ? b1 : b2;
    if (mat < 2) {
      short* dst = (short*)(mat == 0 ? O0 : O1);
#pragma unroll
      for (int mf = 0; mf < 4; ++mf)
#pragma unroll
        for (int nf = 0; nf < 4; ++nf) {
          const int col = nc0 + wn * 64 + nf * 16 + l15;
          const float bv = bias[col];
          const int h = col >> 6, hd = col & 63;
#pragma unroll
          for (int rr = 0; rr < 4; ++rr) {
            const int row = m0 + wm * 64 + mf * 16 + lg * 4 + rr;
            const int b = row >> 11, s = row & 2047;
            dst[((size_t)(b * 16 + h) * 2048 + s) * 64 + hd] = f2bf(acc[mf][nf][rr] + bv);
          }
        }
    } else {
      // V: write transposed AND k-permuted into Vt [B*16+h][64][2048]:
      // within each 32-k group, stored pos = lg*8 + hi*4 + e for k = hi*16+lg*4+e
      short* dst = (short*)O2;
#pragma unroll
      for (int mf = 0; mf < 4; ++mf) {
        const int rowb = m0 + wm * 64 + mf * 16 + lg * 4;
        const int b = rowb >> 11, s = rowb & 2047;
        const int s2 = (s & ~31) | (((s >> 2) & 3) << 3) | (((s >> 4) & 1) << 2);
#pragma unroll
        for (int nf = 0; nf < 4; ++nf) {
          const int col = nc0 + wn * 64 + nf * 16 + l15;
          const float bv = bias[col];
          const int h = col >> 6, hd = col & 63;
          short4 sv;
          sv.x = f2bf(acc[mf][nf][0] + bv);
          sv.y = f2bf(acc[mf][nf][1] + bv);
          sv.z = f2bf(acc[mf][nf][2] + bv);
          sv.w = f2bf(acc[mf][nf][3] + bv);
          *(short4*)&dst[((size_t)(b * 16 + h) * 64 + hd) * 2048 + s2] = sv;
        }
      }
    }
  }
}

// ---------------- flash causal attention, fixed-shift softmax ----------------
// Q,K: [64bh][2048][64] bf16; Vt: [64bh][64][2048] bf16 (k-permuted);
// out: [B,S,1024] bf16.  Unnormalized p = exp2(s); row sums via MFMA
// ones-column (psacc layout == o layout -> shuffle-free normalize).
// 3-buffer LDS ring, stage(kt+2) during tile kt, gate vmcnt(4).
__global__ __launch_bounds__(256) void attn_kernel(const short* __restrict__ Q,
                                                   const short* __restrict__ K,
                                                   const short* __restrict__ Vt,
                                                   short* __restrict__ Oout) {
  __shared__ short Ks[3][4096];
  __shared__ short Vs[3][4096];
  // grid map: same-bh blocks share an XCD (bh&7 == g&7); heavy jq first
  const int g = (int)blockIdx.x;
  const int bh = (((g >> 3) & 7) << 3) | (g & 7);
  const int jq = 15 - (g >> 6);
  const int q0 = jq * 128;
  const int tid = threadIdx.x;
  const int lane = tid & 63, w = tid >> 6;
  const int l15 = lane & 15, lg = lane >> 4;
  const short* Qb = Q + (size_t)bh * 2048 * 64;
  const short* Kb = K + (size_t)bh * 2048 * 64;
  const short* Vb = Vt + (size_t)bh * 64 * 2048;
  const int b = bh >> 4, h = bh & 15;
  const float SC = 0.18033688011112042f;  // 0.125 * log2(e)
  const int qg0 = q0 + w * 32;

  // Q fragments in registers, pre-scaled by 0.125*log2e
  bf16x8 qf[2][2];
#pragma unroll
  for (int qs = 0; qs < 2; ++qs)
#pragma unroll
    for (int kk = 0; kk < 2; ++kk) {
      bf16x8 rq =
          *(const bf16x8*)&Qb[(size_t)(qg0 + qs * 16 + l15) * 64 + kk * 32 + lg * 8];
      union { uint32_t u[4]; bf16x8 v; } sq;
#pragma unroll
      for (int d = 0; d < 4; ++d)
        sq.u[d] = cvt_pk_bf16(bf2f(rq[2 * d]) * SC, bf2f(rq[2 * d + 1]) * SC);
      qf[qs][kk] = sq.v;
    }

  // ones B-frag for row-sum MFMA
  union { short s[8]; bf16x8 v; } one_u;
#pragma unroll
  for (int i = 0; i < 8; ++i) one_u.s[i] = (short)0x3F80;

  // per-lane pre-swizzled staging sources (2 K-loads + 2 V-loads per wave)
  const short* kg[2];
  const short* vg[2];
#pragma unroll
  for (int i = 0; i < 2; ++i) {
    const int P = (w * 2 + i) * 64 + lane;  // physical 16B block 0..511
    const int L = P ^ ((P >> 3) & 7);       // logical: row L>>3, blk-col L&7
    kg[i] = Kb + (size_t)(L >> 3) * 64 + (L & 7) * 8;
    vg[i] = Vb + (size_t)(L >> 3) * 2048 + (L & 7) * 8;
  }

  // swizzled LDS read offsets (both K and V are b128)
  int kcol[2], vcol[2];
#pragma unroll
  for (int kk = 0; kk < 2; ++kk) {
    kcol[kk] = (((kk * 4 + lg) ^ (l15 & 7)) << 3);
    vcol[kk] = kcol[kk];
  }

  f32x4 o[2][4];
#pragma unroll
  for (int i = 0; i < 2; ++i)
#pragma unroll
    for (int j = 0; j < 4; ++j) o[i][j] = (f32x4){0.f, 0.f, 0.f, 0.f};
  f32x4 psacc[2] = {(f32x4){0.f, 0.f, 0.f, 0.f}, (f32x4){0.f, 0.f, 0.f, 0.f}};

  auto stageKV = [&](int bi, int kt) {
#pragma unroll
    for (int i = 0; i < 2; ++i) {
      gload_lds16(kg[i] + (size_t)kt * 4096, &Ks[bi][(w * 2 + i) * 512]);
      gload_lds16(vg[i] + kt * 64, &Vs[bi][(w * 2 + i) * 512]);
    }
  };

  const int nkt = 2 * jq + 2;
  // prologue: 2 tiles in flight
  stageKV(0, 0);
  stageKV(1, 1);

  int cur = 0;
  for (int kt = 0; kt < nkt; ++kt) {
    if (kt + 1 < nkt) {
      GATE(4)   // tile kt's 4 loads done; kt+1's stay in flight
    } else {
      GATE(0)
    }
    if (kt + 2 < nkt) {
      int nb = cur + 2; if (nb >= 3) nb -= 3;
      stageKV(nb, kt + 2);  // overwrites buffer read at kt-1 (published by GATE)
    }

    if (kt * 64 <= qg0 + 31) {  // wave-uniform skip of fully-masked tiles
      const short* Kc = &Ks[cur][0];
      const short* Vc = &Vs[cur][0];

      // S^T = K @ Q^T : k = kt*64 + t*16 + lg*4 + r, q col = l15 (+16*qs)
      f32x4 sacc[4][2];
#pragma unroll
      for (int t = 0; t < 4; ++t)
#pragma unroll
        for (int qs = 0; qs < 2; ++qs) sacc[t][qs] = (f32x4){0.f, 0.f, 0.f, 0.f};
      __builtin_amdgcn_s_setprio(1);
#pragma unroll
      for (int t = 0; t < 4; ++t) {
        const int krow = (t * 16 + l15) * 64;
#pragma unroll
        for (int kk = 0; kk < 2; ++kk) {
          bf16x8 kf = *(const bf16x8*)&Kc[krow + kcol[kk]];
#pragma unroll
          for (int qs = 0; qs < 2; ++qs)
            sacc[t][qs] = __builtin_amdgcn_mfma_f32_16x16x32_bf16(kf, qf[qs][kk],
                                                                  sacc[t][qs], 0, 0, 0);
        }
      }
      __builtin_amdgcn_s_setprio(0);

      // causal mask — only the wave's diagonal region (wave-uniform test)
      if (kt * 64 + 63 > qg0) {
#pragma unroll
        for (int t = 0; t < 4; ++t)
#pragma unroll
          for (int qs = 0; qs < 2; ++qs)
#pragma unroll
            for (int r = 0; r < 4; ++r) {
              const int kg_ = kt * 64 + t * 16 + lg * 4 + r;
              const int qg = qg0 + qs * 16 + l15;
              if (kg_ > qg) sacc[t][qs][r] = -3e38f;
            }
      }

      // fixed-shift softmax: p = exp2(s); pack to bf16 A-frags
      bf16x8 pa[2][2];
#pragma unroll
      for (int qs = 0; qs < 2; ++qs) {
#pragma unroll
        for (int t = 0; t < 4; ++t)
#pragma unroll
          for (int r = 0; r < 4; ++r)
            sacc[t][qs][r] = __builtin_amdgcn_exp2f(sacc[t][qs][r]);
#pragma unroll
        for (int kk = 0; kk < 2; ++kk) {
          union { uint32_t u[4]; bf16x8 v; } pw;
          pw.u[0] = cvt_pk_bf16(sacc[2 * kk][qs][0], sacc[2 * kk][qs][1]);
          pw.u[1] = cvt_pk_bf16(sacc[2 * kk][qs][2], sacc[2 * kk][qs][3]);
          pw.u[2] = cvt_pk_bf16(sacc[2 * kk + 1][qs][0], sacc[2 * kk + 1][qs][1]);
          pw.u[3] = cvt_pk_bf16(sacc[2 * kk + 1][qs][2], sacc[2 * kk + 1][qs][3]);
          pa[qs][kk] = pw.v;
        }
      }

      // PV + row-sum MFMAs (one setprio cluster)
      __builtin_amdgcn_s_setprio(1);
#pragma unroll
      for (int ds = 0; ds < 4; ++ds) {
        const int vrow = (ds * 16 + l15) * 64;
#pragma unroll
        for (int kk = 0; kk < 2; ++kk) {
          bf16x8 vf = *(const bf16x8*)&Vc[vrow + vcol[kk]];
#pragma unroll
          for (int qs = 0; qs < 2; ++qs)
            o[qs][ds] = __builtin_amdgcn_mfma_f32_16x16x32_bf16(pa[qs][kk], vf,
                                                                o[qs][ds], 0, 0, 0);
        }
      }
#pragma unroll
      for (int qs = 0; qs < 2; ++qs)
#pragma unroll
        for (int kk = 0; kk < 2; ++kk)
          psacc[qs] = __builtin_amdgcn_mfma_f32_16x16x32_bf16(pa[qs][kk], one_u.v,
                                                              psacc[qs], 0, 0, 0);
      __builtin_amdgcn_s_setprio(0);
    }

    cur = cur + 1 == 3 ? 0 : cur + 1;
  }

  // normalize + write; psacc layout == o layout (row = lg*4+r) -> lane-local
#pragma unroll
  for (int qs = 0; qs < 2; ++qs) {
    float inv[4];
#pragma unroll
    for (int r = 0; r < 4; ++r) inv[r] = 1.f / psacc[qs][r];
#pragma unroll
    for (int ds = 0; ds < 4; ++ds)
#pragma unroll
      for (int r = 0; r < 4; ++r) {
        const int qg = q0 + w * 32 + qs * 16 + lg * 4 + r;
        const int col = h * 64 + ds * 16 + l15;
        Oout[((size_t)(b * 2048 + qg)) * 1024 + col] = f2bf(o[qs][ds][r] * inv[r]);
      }
  }
}

// ---------------------------------------------------------------------------
extern "C" void kernel_launch(void* const* d_in, const int* in_sizes, int n_in,
                              void* d_out, int out_size, void* d_ws, size_t ws_size,
                              hipStream_t stream) {
  const float* hs = (const float*)d_in[0];
  const float* Wq = (const float*)d_in[1];
  const float* bq = (const float*)d_in[2];
  const float* Wk = (const float*)d_in[3];
  const float* bk = (const float*)d_in[4];
  const float* Wv = (const float*)d_in[5];
  const float* bv = (const float*)d_in[6];
  const float* Wo = (const float*)d_in[7];
  const float* bo = (const float*)d_in[8];

  char* ws = (char*)d_ws;
  short* Xbf = (short*)(ws + 0);                  // 16 MB, reused as attn out
  short* Qb  = (short*)(ws + ((size_t)16 << 20)); // 16 MB
  short* Kb  = (short*)(ws + ((size_t)32 << 20)); // 16 MB
  short* Vtb = (short*)(ws + ((size_t)48 << 20)); // 16 MB
  short* Wts = (short*)(ws + ((size_t)64 << 20)); // 8 MB: Wqt|Wkt|Wvt|Wot
  short* Wot = Wts + ((size_t)3 << 20);

  cvt_bf16_kernel<<<2048, 256, 0, stream>>>(hs, Xbf, (8192 * 1024) / 4);
  wt4_kernel<<<dim3(16, 16, 4), 256, 0, stream>>>(Wq, Wk, Wv, Wo, Wts);

  // QKV: M=8192 (64 tiles), N=3072 (24 tiles) -> 1536 blocks (6/CU)
  gemm2<0><<<1536, 256, 0, stream>>>(Xbf, Wts, bq, bk, bv, Qb, Kb, Vtb);

  attn_kernel<<<1024, 256, 0, stream>>>(Qb, Kb, Vtb, Xbf);

  // out-proj: M=8192 (64), N=1024 (8) -> 512 blocks (2/CU)
  gemm2<1><<<512, 256, 0, stream>>>(Xbf, Wot, bo, nullptr, nullptr,
                                    (float*)d_out, nullptr, nullptr);
}

// Round 9
// 148.596 us; speedup vs baseline: 1.0490x; 1.0490x over previous
//
#include <hip/hip_runtime.h>
#include <stdint.h>

// ---------------------------------------------------------------------------
// GPT-2 attention block on gfx950.  B=4, S=2048, D=1024, H=16, HD=64.
//   1. cvt_bf16:  X fp32 -> bf16
//   2. wt4:       {Wq,Wk,Wv,Wo} fp32 [K][N] -> bf16 [N][K]
//   3. gemm8<0>:  QKV = X@[Wq|Wk|Wv]+b  (8-phase-style schedule: 256x128,
//                 BK=64, 8 waves 4Mx2N, 3-buf LDS ring 144KB, 4 quadrant-
//                 phases/K-tile, counted vmcnt(6), per-phase barriers+setprio)
//   4. attn:      flash causal attention, fixed-shift softmax, 3-buf ring,
//                 row-sums via MFMA ones-column.
//   5. gemm8<1>:  out = attn@Wo + bo, fp32
// ---------------------------------------------------------------------------

#define GAS __attribute__((address_space(1)))
#define LAS __attribute__((address_space(3)))

typedef __attribute__((ext_vector_type(4))) float f32x4;
typedef __attribute__((ext_vector_type(8))) short bf16x8;

__device__ __forceinline__ short f2bf(float f) {
  union { float f; uint32_t u; } v; v.f = f;
  uint32_t r = v.u + 0x7fffu + ((v.u >> 16) & 1u);  // RNE
  return (short)(r >> 16);
}

__device__ __forceinline__ float bf2f(short s) {
  union { uint32_t u; float f; } v;
  v.u = ((uint32_t)(uint16_t)s) << 16;
  return v.f;
}

__device__ __forceinline__ uint32_t cvt_pk_bf16(float lo, float hi) {
  uint32_t r;
  asm("v_cvt_pk_bf16_f32 %0, %1, %2" : "=v"(r) : "v"(lo), "v"(hi));
  return r;
}

__device__ __forceinline__ void gload_lds16(const void* g, void* l) {
  // 16B per lane; LDS dest = wave-uniform base + lane*16 (linear)
  __builtin_amdgcn_global_load_lds((const GAS void*)g, (LAS void*)l, 16, 0, 0);
}

// Group gate: counted vmcnt + raw barrier; sched_barrier pins motion both ways.
#define GATE(N)                                            \
  __builtin_amdgcn_sched_barrier(0);                       \
  asm volatile("s_waitcnt vmcnt(" #N ")" ::: "memory");    \
  __builtin_amdgcn_s_barrier();                            \
  __builtin_amdgcn_sched_barrier(0);

// ---------------- fp32 -> bf16 convert ----------------
__global__ __launch_bounds__(256) void cvt_bf16_kernel(const float* __restrict__ in,
                                                       short* __restrict__ out, int n4) {
  int i = blockIdx.x * blockDim.x + threadIdx.x;
  int stride = gridDim.x * blockDim.x;
  for (int idx = i; idx < n4; idx += stride) {
    float4 v = ((const float4*)in)[idx];
    short4 o;
    o.x = f2bf(v.x); o.y = f2bf(v.y); o.z = f2bf(v.z); o.w = f2bf(v.w);
    ((short4*)out)[idx] = o;
  }
}

// ---------------- 4x W [1024][1024] fp32 -> Wt bf16 [N][K] ----------------
__global__ __launch_bounds__(256) void wt4_kernel(const float* __restrict__ W0,
                                                  const float* __restrict__ W1,
                                                  const float* __restrict__ W2,
                                                  const float* __restrict__ W3,
                                                  short* __restrict__ Wt) {
  __shared__ short tile[64][65];
  const float* W = (blockIdx.z == 0) ? W0 : (blockIdx.z == 1) ? W1
                   : (blockIdx.z == 2) ? W2 : W3;
  short* dst = Wt + ((size_t)blockIdx.z << 20);
  const int k0 = blockIdx.x * 64, n0 = blockIdx.y * 64;
  const int t = threadIdx.x;
#pragma unroll
  for (int i = 0; i < 16; ++i) {
    int r = (t >> 6) + i * 4, c = t & 63;
    tile[r][c] = f2bf(W[(size_t)(k0 + r) * 1024 + n0 + c]);
  }
  __syncthreads();
#pragma unroll
  for (int i = 0; i < 16; ++i) {
    int r = (t >> 6) + i * 4, c = t & 63;
    dst[(size_t)(n0 + r) * 1024 + k0 + c] = tile[c][r];
  }
}

// ---------------- 8-phase-style deep-pipelined bf16 GEMM ----------------
// C[M,N] = A[M,1024] @ Bt[N,1024]^T + bias.  BM=256, BN=128, BK=64.
// 512 thr = 8 waves (4M x 2N), wave tile 64x64 (4x4 16x16 frags).
// LDS: 3-buffer ring, 48KB each (A 32KB + B 16KB) = 144KB, 1 block/CU.
// Per K-tile: GATE(vmcnt 6) then 4 quadrant-phases; each phase issues its
// ds_reads + a slice of tile j+2's global_load_lds, then barrier -> setprio ->
// 8 MFMA -> barrier.  Tile j+1 (6 loads) stays in flight across the gate.
// Swizzle (BK=64): phys chunk = logical chunk ^ (row&7) -> conflict-free b128.
template <int MODE>
__global__ __launch_bounds__(512, 2) void gemm8(const short* __restrict__ A,
                                                const short* __restrict__ Bt,
                                                const float* __restrict__ b0,
                                                const float* __restrict__ b1,
                                                const float* __restrict__ b2,
                                                void* __restrict__ O0,
                                                void* __restrict__ O1,
                                                void* __restrict__ O2) {
  __shared__ short lds[3][24576];  // [buf][ A: 0..16383 | B: 16384..24575 ]
  const int xcd = (int)blockIdx.x & 7;
  const int t = (int)blockIdx.x >> 3;
  const int m0 = (xcd * 4 + (t & 3)) * 256;  // 4 m-tiles per XCD (2MB, L2-fit)
  const int n0 = (t >> 2) * 128;
  const int tid = threadIdx.x;
  const int lane = tid & 63, w = tid >> 6;
  const int l15 = lane & 15, lg = lane >> 4;
  const int wm = w >> 1, wn = w & 1;  // 4M x 2N wave grid

  // staging sources, pre-swizzled per-lane.  A: 2048 16B blocks (4/thread),
  // B: 1024 (2/thread).  phys block P -> row=P>>3, c_log=(P&7)^(row&7).
  const short* ag[4];
#pragma unroll
  for (int i = 0; i < 4; ++i) {
    const int P = i * 512 + tid;
    const int row = P >> 3, cl = (P & 7) ^ (row & 7);
    ag[i] = A + (size_t)(m0 + row) * 1024 + cl * 8;
  }
  const short* bg[2];
#pragma unroll
  for (int i = 0; i < 2; ++i) {
    const int P = i * 512 + tid;
    const int row = P >> 3, cl = (P & 7) ^ (row & 7);
    bg[i] = Bt + (size_t)(n0 + row) * 1024 + cl * 8;
  }

  // ds_read offsets (shorts) for kk=0; kk=1 = ^32 (chunk bit2 flip = 64B)
  int aof[4], bof[4];
#pragma unroll
  for (int f = 0; f < 4; ++f) {
    const int ra = wm * 64 + f * 16 + l15;
    aof[f] = ra * 64 + ((lg ^ (l15 & 7)) * 8);
    const int rb = wn * 64 + f * 16 + l15;
    bof[f] = 16384 + rb * 64 + ((lg ^ (l15 & 7)) * 8);
  }

  f32x4 acc[4][4];
#pragma unroll
  for (int i = 0; i < 4; ++i)
#pragma unroll
    for (int j = 0; j < 4; ++j) acc[i][j] = (f32x4){0.f, 0.f, 0.f, 0.f};

  auto stageA = [&](int bi_, int kt, int i) {
    gload_lds16(ag[i] + kt * 64, &lds[bi_][(i * 512 + w * 64) * 8]);
  };
  auto stageB = [&](int bi_, int kt, int i) {
    gload_lds16(bg[i] + kt * 64, &lds[bi_][16384 + (i * 512 + w * 64) * 8]);
  };
  auto stageTile = [&](int bi_, int kt) {  // 6 loads, fixed order (vmcnt group)
    stageA(bi_, kt, 0); stageA(bi_, kt, 1); stageA(bi_, kt, 2); stageA(bi_, kt, 3);
    stageB(bi_, kt, 0); stageB(bi_, kt, 1);
  };

#define RA(mf, kk) (*(const bf16x8*)&lds[bi][aof[mf] ^ ((kk) * 32)])
#define RB(nf, kk) (*(const bf16x8*)&lds[bi][bof[nf] ^ ((kk) * 32)])
#define MM(mf, nf)                                                             \
  acc[mf][nf] = __builtin_amdgcn_mfma_f32_16x16x32_bf16(af[mf][0], bfr[nf][0], \
                                                        acc[mf][nf], 0, 0, 0); \
  acc[mf][nf] = __builtin_amdgcn_mfma_f32_16x16x32_bf16(af[mf][1], bfr[nf][1], \
                                                        acc[mf][nf], 0, 0, 0);
#define PH_SYNC                     \
  __builtin_amdgcn_s_barrier();     \
  __builtin_amdgcn_s_setprio(1);
#define PH_END                      \
  __builtin_amdgcn_s_setprio(0);    \
  __builtin_amdgcn_s_barrier();

  // prologue: 2 tiles in flight (12 loads/thread)
  stageTile(0, 0);
  stageTile(1, 1);

  bf16x8 af[4][2], bfr[4][2];
  int bi = 0;
  for (int j = 0; j < 16; ++j) {
    if (j < 15) { GATE(6) } else { GATE(0) }
    const int nb = (bi + 2 >= 3) ? bi - 1 : bi + 2;
    const int ktn = j + 2;
    const bool st = (j < 14);

    // phase 0: quadrant (m0,m1)x(n0,n1); read A01,B01; stage A-slices 0,1
    af[0][0] = RA(0, 0); af[0][1] = RA(0, 1);
    af[1][0] = RA(1, 0); af[1][1] = RA(1, 1);
    bfr[0][0] = RB(0, 0); bfr[0][1] = RB(0, 1);
    bfr[1][0] = RB(1, 0); bfr[1][1] = RB(1, 1);
    if (st) { stageA(nb, ktn, 0); stageA(nb, ktn, 1); }
    PH_SYNC; MM(0, 0) MM(0, 1) MM(1, 0) MM(1, 1) PH_END;

    // phase 1: (m2,m3)x(n0,n1); read A23; stage A-slices 2,3
    af[2][0] = RA(2, 0); af[2][1] = RA(2, 1);
    af[3][0] = RA(3, 0); af[3][1] = RA(3, 1);
    if (st) { stageA(nb, ktn, 2); stageA(nb, ktn, 3); }
    PH_SYNC; MM(2, 0) MM(2, 1) MM(3, 0) MM(3, 1) PH_END;

    // phase 2: (m2,m3)x(n2,n3); read B23; stage B-slice 0
    bfr[2][0] = RB(2, 0); bfr[2][1] = RB(2, 1);
    bfr[3][0] = RB(3, 0); bfr[3][1] = RB(3, 1);
    if (st) stageB(nb, ktn, 0);
    PH_SYNC; MM(2, 2) MM(2, 3) MM(3, 2) MM(3, 3) PH_END;

    // phase 3: (m0,m1)x(n2,n3); frags already in regs; stage B-slice 1
    if (st) stageB(nb, ktn, 1);
    PH_SYNC; MM(0, 2) MM(0, 3) MM(1, 2) MM(1, 3) PH_END;

    bi = (bi + 1 == 3) ? 0 : bi + 1;
  }
#undef RA
#undef RB
#undef MM
#undef PH_SYNC
#undef PH_END

  // ---------------- epilogue; frag: row = lg*4+rr, col = l15 ----------------
  if (MODE == 1) {
    float* dst = (float*)O0;
#pragma unroll
    for (int mf = 0; mf < 4; ++mf)
#pragma unroll
      for (int nf = 0; nf < 4; ++nf) {
        const int col = n0 + wn * 64 + nf * 16 + l15;
        const float bv = b0[col];
#pragma unroll
        for (int rr = 0; rr < 4; ++rr) {
          const int row = m0 + wm * 64 + mf * 16 + lg * 4 + rr;
          dst[(size_t)row * 1024 + col] = acc[mf][nf][rr] + bv;
        }
      }
  } else {
    const int mat = n0 >> 10;  // 0=Q 1=K 2=V
    const int nc0 = n0 & 1023;
    const float* bias = (mat == 0) ? b0 : (mat == 1) ? b1 : b2;
    if (mat < 2) {
      short* dst = (short*)(mat == 0 ? O0 : O1);
#pragma unroll
      for (int mf = 0; mf < 4; ++mf)
#pragma unroll
        for (int nf = 0; nf < 4; ++nf) {
          const int col = nc0 + wn * 64 + nf * 16 + l15;
          const float bv = bias[col];
          const int h = col >> 6, hd = col & 63;
#pragma unroll
          for (int rr = 0; rr < 4; ++rr) {
            const int row = m0 + wm * 64 + mf * 16 + lg * 4 + rr;
            const int b = row >> 11, s = row & 2047;
            dst[((size_t)(b * 16 + h) * 2048 + s) * 64 + hd] = f2bf(acc[mf][nf][rr] + bv);
          }
        }
    } else {
      // V: write transposed AND k-permuted into Vt [B*16+h][64][2048]:
      // within each 32-k group, stored pos = lg*8 + hi*4 + e for k = hi*16+lg*4+e
      short* dst = (short*)O2;
#pragma unroll
      for (int mf = 0; mf < 4; ++mf) {
        const int rowb = m0 + wm * 64 + mf * 16 + lg * 4;
        const int b = rowb >> 11, s = rowb & 2047;
        const int s2 = (s & ~31) | (((s >> 2) & 3) << 3) | (((s >> 4) & 1) << 2);
#pragma unroll
        for (int nf = 0; nf < 4; ++nf) {
          const int col = nc0 + wn * 64 + nf * 16 + l15;
          const float bv = bias[col];
          const int h = col >> 6, hd = col & 63;
          short4 sv;
          sv.x = f2bf(acc[mf][nf][0] + bv);
          sv.y = f2bf(acc[mf][nf][1] + bv);
          sv.z = f2bf(acc[mf][nf][2] + bv);
          sv.w = f2bf(acc[mf][nf][3] + bv);
          *(short4*)&dst[((size_t)(b * 16 + h) * 64 + hd) * 2048 + s2] = sv;
        }
      }
    }
  }
}

// ---------------- flash causal attention, fixed-shift softmax ----------------
// Q,K: [64bh][2048][64] bf16; Vt: [64bh][64][2048] bf16 (k-permuted);
// out: [B,S,1024] bf16.  Unnormalized p = exp2(s); row sums via MFMA
// ones-column (psacc layout == o layout -> shuffle-free normalize).
// 3-buffer LDS ring, stage(kt+2) during tile kt, gate vmcnt(4).
__global__ __launch_bounds__(256) void attn_kernel(const short* __restrict__ Q,
                                                   const short* __restrict__ K,
                                                   const short* __restrict__ Vt,
                                                   short* __restrict__ Oout) {
  __shared__ short Ks[3][4096];
  __shared__ short Vs[3][4096];
  // grid map: same-bh blocks share an XCD (bh&7 == g&7); heavy jq first
  const int g = (int)blockIdx.x;
  const int bh = (((g >> 3) & 7) << 3) | (g & 7);
  const int jq = 15 - (g >> 6);
  const int q0 = jq * 128;
  const int tid = threadIdx.x;
  const int lane = tid & 63, w = tid >> 6;
  const int l15 = lane & 15, lg = lane >> 4;
  const short* Qb = Q + (size_t)bh * 2048 * 64;
  const short* Kb = K + (size_t)bh * 2048 * 64;
  const short* Vb = Vt + (size_t)bh * 64 * 2048;
  const int b = bh >> 4, h = bh & 15;
  const float SC = 0.18033688011112042f;  // 0.125 * log2(e)
  const int qg0 = q0 + w * 32;

  // Q fragments in registers, pre-scaled by 0.125*log2e
  bf16x8 qf[2][2];
#pragma unroll
  for (int qs = 0; qs < 2; ++qs)
#pragma unroll
    for (int kk = 0; kk < 2; ++kk) {
      bf16x8 rq =
          *(const bf16x8*)&Qb[(size_t)(qg0 + qs * 16 + l15) * 64 + kk * 32 + lg * 8];
      union { uint32_t u[4]; bf16x8 v; } sq;
#pragma unroll
      for (int d = 0; d < 4; ++d)
        sq.u[d] = cvt_pk_bf16(bf2f(rq[2 * d]) * SC, bf2f(rq[2 * d + 1]) * SC);
      qf[qs][kk] = sq.v;
    }

  // ones B-frag for row-sum MFMA
  union { short s[8]; bf16x8 v; } one_u;
#pragma unroll
  for (int i = 0; i < 8; ++i) one_u.s[i] = (short)0x3F80;

  // per-lane pre-swizzled staging sources (2 K-loads + 2 V-loads per wave)
  const short* kg[2];
  const short* vg[2];
#pragma unroll
  for (int i = 0; i < 2; ++i) {
    const int P = (w * 2 + i) * 64 + lane;  // physical 16B block 0..511
    const int L = P ^ ((P >> 3) & 7);       // logical: row L>>3, blk-col L&7
    kg[i] = Kb + (size_t)(L >> 3) * 64 + (L & 7) * 8;
    vg[i] = Vb + (size_t)(L >> 3) * 2048 + (L & 7) * 8;
  }

  // swizzled LDS read offsets (both K and V are b128)
  int kcol[2], vcol[2];
#pragma unroll
  for (int kk = 0; kk < 2; ++kk) {
    kcol[kk] = (((kk * 4 + lg) ^ (l15 & 7)) << 3);
    vcol[kk] = kcol[kk];
  }

  f32x4 o[2][4];
#pragma unroll
  for (int i = 0; i < 2; ++i)
#pragma unroll
    for (int j = 0; j < 4; ++j) o[i][j] = (f32x4){0.f, 0.f, 0.f, 0.f};
  f32x4 psacc[2] = {(f32x4){0.f, 0.f, 0.f, 0.f}, (f32x4){0.f, 0.f, 0.f, 0.f}};

  auto stageKV = [&](int bi, int kt) {
#pragma unroll
    for (int i = 0; i < 2; ++i) {
      gload_lds16(kg[i] + (size_t)kt * 4096, &Ks[bi][(w * 2 + i) * 512]);
      gload_lds16(vg[i] + kt * 64, &Vs[bi][(w * 2 + i) * 512]);
    }
  };

  const int nkt = 2 * jq + 2;
  // prologue: 2 tiles in flight
  stageKV(0, 0);
  stageKV(1, 1);

  int cur = 0;
  for (int kt = 0; kt < nkt; ++kt) {
    if (kt + 1 < nkt) {
      GATE(4)   // tile kt's 4 loads done; kt+1's stay in flight
    } else {
      GATE(0)
    }
    if (kt + 2 < nkt) {
      int nb = cur + 2; if (nb >= 3) nb -= 3;
      stageKV(nb, kt + 2);  // overwrites buffer read at kt-1 (published by GATE)
    }

    if (kt * 64 <= qg0 + 31) {  // wave-uniform skip of fully-masked tiles
      const short* Kc = &Ks[cur][0];
      const short* Vc = &Vs[cur][0];

      // S^T = K @ Q^T : k = kt*64 + t*16 + lg*4 + r, q col = l15 (+16*qs)
      f32x4 sacc[4][2];
#pragma unroll
      for (int t = 0; t < 4; ++t)
#pragma unroll
        for (int qs = 0; qs < 2; ++qs) sacc[t][qs] = (f32x4){0.f, 0.f, 0.f, 0.f};
      __builtin_amdgcn_s_setprio(1);
#pragma unroll
      for (int t = 0; t < 4; ++t) {
        const int krow = (t * 16 + l15) * 64;
#pragma unroll
        for (int kk = 0; kk < 2; ++kk) {
          bf16x8 kf = *(const bf16x8*)&Kc[krow + kcol[kk]];
#pragma unroll
          for (int qs = 0; qs < 2; ++qs)
            sacc[t][qs] = __builtin_amdgcn_mfma_f32_16x16x32_bf16(kf, qf[qs][kk],
                                                                  sacc[t][qs], 0, 0, 0);
        }
      }
      __builtin_amdgcn_s_setprio(0);

      // causal mask — only the wave's diagonal region (wave-uniform test)
      if (kt * 64 + 63 > qg0) {
#pragma unroll
        for (int t = 0; t < 4; ++t)
#pragma unroll
          for (int qs = 0; qs < 2; ++qs)
#pragma unroll
            for (int r = 0; r < 4; ++r) {
              const int kg_ = kt * 64 + t * 16 + lg * 4 + r;
              const int qg = qg0 + qs * 16 + l15;
              if (kg_ > qg) sacc[t][qs][r] = -3e38f;
            }
      }

      // fixed-shift softmax: p = exp2(s); pack to bf16 A-frags
      bf16x8 pa[2][2];
#pragma unroll
      for (int qs = 0; qs < 2; ++qs) {
#pragma unroll
        for (int t = 0; t < 4; ++t)
#pragma unroll
          for (int r = 0; r < 4; ++r)
            sacc[t][qs][r] = __builtin_amdgcn_exp2f(sacc[t][qs][r]);
#pragma unroll
        for (int kk = 0; kk < 2; ++kk) {
          union { uint32_t u[4]; bf16x8 v; } pw;
          pw.u[0] = cvt_pk_bf16(sacc[2 * kk][qs][0], sacc[2 * kk][qs][1]);
          pw.u[1] = cvt_pk_bf16(sacc[2 * kk][qs][2], sacc[2 * kk][qs][3]);
          pw.u[2] = cvt_pk_bf16(sacc[2 * kk + 1][qs][0], sacc[2 * kk + 1][qs][1]);
          pw.u[3] = cvt_pk_bf16(sacc[2 * kk + 1][qs][2], sacc[2 * kk + 1][qs][3]);
          pa[qs][kk] = pw.v;
        }
      }

      // PV + row-sum MFMAs (one setprio cluster)
      __builtin_amdgcn_s_setprio(1);
#pragma unroll
      for (int ds = 0; ds < 4; ++ds) {
        const int vrow = (ds * 16 + l15) * 64;
#pragma unroll
        for (int kk = 0; kk < 2; ++kk) {
          bf16x8 vf = *(const bf16x8*)&Vc[vrow + vcol[kk]];
#pragma unroll
          for (int qs = 0; qs < 2; ++qs)
            o[qs][ds] = __builtin_amdgcn_mfma_f32_16x16x32_bf16(pa[qs][kk], vf,
                                                                o[qs][ds], 0, 0, 0);
        }
      }
#pragma unroll
      for (int qs = 0; qs < 2; ++qs)
#pragma unroll
        for (int kk = 0; kk < 2; ++kk)
          psacc[qs] = __builtin_amdgcn_mfma_f32_16x16x32_bf16(pa[qs][kk], one_u.v,
                                                              psacc[qs], 0, 0, 0);
      __builtin_amdgcn_s_setprio(0);
    }

    cur = cur + 1 == 3 ? 0 : cur + 1;
  }

  // normalize + write; psacc layout == o layout (row = lg*4+r) -> lane-local
#pragma unroll
  for (int qs = 0; qs < 2; ++qs) {
    float inv[4];
#pragma unroll
    for (int r = 0; r < 4; ++r) inv[r] = 1.f / psacc[qs][r];
#pragma unroll
    for (int ds = 0; ds < 4; ++ds)
#pragma unroll
      for (int r = 0; r < 4; ++r) {
        const int qg = q0 + w * 32 + qs * 16 + lg * 4 + r;
        const int col = h * 64 + ds * 16 + l15;
        Oout[((size_t)(b * 2048 + qg)) * 1024 + col] = f2bf(o[qs][ds][r] * inv[r]);
      }
  }
}

// ---------------------------------------------------------------------------
extern "C" void kernel_launch(void* const* d_in, const int* in_sizes, int n_in,
                              void* d_out, int out_size, void* d_ws, size_t ws_size,
                              hipStream_t stream) {
  const float* hs = (const float*)d_in[0];
  const float* Wq = (const float*)d_in[1];
  const float* bq = (const float*)d_in[2];
  const float* Wk = (const float*)d_in[3];
  const float* bk = (const float*)d_in[4];
  const float* Wv = (const float*)d_in[5];
  const float* bv = (const float*)d_in[6];
  const float* Wo = (const float*)d_in[7];
  const float* bo = (const float*)d_in[8];

  char* ws = (char*)d_ws;
  short* Xbf = (short*)(ws + 0);                  // 16 MB, reused as attn out
  short* Qb  = (short*)(ws + ((size_t)16 << 20)); // 16 MB
  short* Kb  = (short*)(ws + ((size_t)32 << 20)); // 16 MB
  short* Vtb = (short*)(ws + ((size_t)48 << 20)); // 16 MB
  short* Wts = (short*)(ws + ((size_t)64 << 20)); // 8 MB: Wqt|Wkt|Wvt|Wot
  short* Wot = Wts + ((size_t)3 << 20);

  cvt_bf16_kernel<<<2048, 256, 0, stream>>>(hs, Xbf, (8192 * 1024) / 4);
  wt4_kernel<<<dim3(16, 16, 4), 256, 0, stream>>>(Wq, Wk, Wv, Wo, Wts);

  // QKV: M=8192 (32 tiles of 256), N=3072 (24 tiles of 128) -> 768 blocks
  gemm8<0><<<768, 512, 0, stream>>>(Xbf, Wts, bq, bk, bv, Qb, Kb, Vtb);

  attn_kernel<<<1024, 256, 0, stream>>>(Qb, Kb, Vtb, Xbf);

  // out-proj: M=8192 (32), N=1024 (8) -> 256 blocks = exactly 1/CU
  gemm8<1><<<256, 512, 0, stream>>>(Xbf, Wot, bo, nullptr, nullptr,
                                    (float*)d_out, nullptr, nullptr);
}